// Round 2
// baseline (3794.377 us; speedup 1.0000x reference)
//
#include <hip/hip_runtime.h>
#include <hip/hip_bf16.h>
#include <cstdint>
#include <cstddef>

// ---------------- problem constants ----------------
constexpr int D   = 1024;
constexpr int H   = 16;
constexpr int HD  = 64;
constexpr int DFF = 4096;
constexpr int T   = 1024;
constexpr int B   = 8;
constexpr int L   = 8;
constexpr int MM  = B * T;      // 8192 tokens
constexpr float LNEPS = 1e-5f;

typedef unsigned short u16;
typedef __attribute__((ext_vector_type(4))) float f32x4;
typedef __attribute__((ext_vector_type(8))) short bf16x8;   // 8 bf16 = 4 VGPR (guide-verified)

__device__ __forceinline__ u16 f2bf(float f) {
  __hip_bfloat16 h = __float2bfloat16(f);
  return __builtin_bit_cast(u16, h);
}

__device__ __forceinline__ void gload_lds16(const void* g, void* l) {
  // async global->LDS, 16B/lane; LDS dest = wave-uniform base + lane*16 (m104/m108)
  __builtin_amdgcn_global_load_lds((const __attribute__((address_space(1))) void*)g,
                                   (__attribute__((address_space(3))) void*)l, 16, 0, 0);
}

// ---------------- GEMM: C[M,N] = A[M,K](bf16) * W[N,K]^T(bf16) + epilogue ----------------
// EPI 0: bf16 plain [M,N], +bias
// EPI 2: bf16 plain, gelu(x+bias) (exact erf)
// EPI 3: fp32 plain, x + bias + res[m,n]
// EPI 4: fused QKV: n in [0,1024) -> Q plain (out), [1024,2048) -> K plain (out2),
//        [2048,3072) -> V^T [B,H,HD,T] (out3); biases bias/bias2/bias3 per segment
template <int EPI>
__global__ __launch_bounds__(256, 2) void gemm_kernel(
    const u16* __restrict__ A, const u16* __restrict__ W,
    const float* __restrict__ bias, const float* __restrict__ bias2,
    const float* __restrict__ bias3, const float* __restrict__ res,
    void* __restrict__ out, void* __restrict__ out2, void* __restrict__ out3,
    int M, int N, int K)
{
  __shared__ u16 As[128 * 64];   // [row][k], 16B chunks XOR-swizzled by (row&7)
  __shared__ u16 Bs[128 * 64];

  // XCD-aware bijective swizzle (nwg % 8 == 0 for every grid we launch)
  const int nwg  = gridDim.x * gridDim.y;
  const int orig = blockIdx.y * gridDim.x + blockIdx.x;
  const int cpx  = nwg >> 3;
  const int lg   = (orig & 7) * cpx + (orig >> 3);
  const int bx   = lg % gridDim.x;
  const int by   = lg / gridDim.x;

  const int tid  = threadIdx.x;
  const int w    = tid >> 6;
  const int lane = tid & 63;
  const int m0   = by * 128;
  const int n0   = bx * 128;
  const int wm   = (w >> 1) * 64;
  const int wn   = (w & 1) * 64;
  const int rlow = lane & 15;
  const int kgrp = lane >> 4;

  f32x4 acc[4][4] = {};

  for (int kt = 0; kt < K; kt += 64) {
    // stage A,B tiles: global source pre-swizzled so swizzled data lands in linear LDS (m173)
#pragma unroll
    for (int i = 0; i < 4; ++i) {
      const int ob    = i * 4096 + w * 1024;        // wave-uniform LDS byte base
      const int o     = ob + lane * 16;             // this lane's LDS byte
      const int row   = o >> 7;                     // 0..127 (128B per row)
      const int chunk = (o >> 4) & 7;               // 16B chunk in row
      const int colel = ((chunk ^ (row & 7)) << 3); // element col in [0,64)
      gload_lds16(A + (size_t)(m0 + row) * K + kt + colel, (char*)As + ob);
      gload_lds16(W + (size_t)(n0 + row) * K + kt + colel, (char*)Bs + ob);
    }
    __syncthreads();

#pragma unroll
    for (int ks = 0; ks < 2; ++ks) {
      bf16x8 af[4], bfr[4];
      const int cg = ks * 4 + kgrp;
#pragma unroll
      for (int f = 0; f < 4; ++f) {
        const int ar = wm + f * 16 + rlow;
        af[f] = *(const bf16x8*)((const char*)As + ar * 128 + ((cg ^ (ar & 7)) << 4));
        const int br = wn + f * 16 + rlow;
        bfr[f] = *(const bf16x8*)((const char*)Bs + br * 128 + ((cg ^ (br & 7)) << 4));
      }
#pragma unroll
      for (int fm = 0; fm < 4; ++fm)
#pragma unroll
        for (int fn = 0; fn < 4; ++fn)
          acc[fm][fn] = __builtin_amdgcn_mfma_f32_16x16x32_bf16(af[fm], bfr[fn], acc[fm][fn], 0, 0, 0);
    }
    __syncthreads();
  }

  // epilogue. C/D layout: col = lane&15, row = (lane>>4)*4 + i   [guide m89/m91]
  const int seg = (n0 + wn) >> 10;  // wave-uniform (wn,n0 multiples of 64; 64-wide col strip)
  const float* bp = bias;
  if constexpr (EPI == 4) bp = (seg == 0) ? bias : (seg == 1 ? bias2 : bias3);

  float bias4[4];
#pragma unroll
  for (int fn = 0; fn < 4; ++fn) {
    int n = n0 + wn + fn * 16 + rlow;
    if constexpr (EPI == 4) n &= 1023;
    bias4[fn] = bp[n];
  }

#pragma unroll
  for (int fm = 0; fm < 4; ++fm) {
#pragma unroll
    for (int i = 0; i < 4; ++i) {
      const int m = m0 + wm + fm * 16 + kgrp * 4 + i;
#pragma unroll
      for (int fn = 0; fn < 4; ++fn) {
        const int n = n0 + wn + fn * 16 + rlow;
        const float v = acc[fm][fn][i] + bias4[fn];
        if constexpr (EPI == 0) {
          ((u16*)out)[(size_t)m * N + n] = f2bf(v);
        } else if constexpr (EPI == 2) {
          const float g = 0.5f * v * (1.0f + erff(v * 0.70710678118654752f));
          ((u16*)out)[(size_t)m * N + n] = f2bf(g);
        } else if constexpr (EPI == 3) {
          ((float*)out)[(size_t)m * N + n] = v + res[(size_t)m * N + n];
        } else {  // EPI == 4
          const int nn = n & 1023;
          if (seg == 0) {
            ((u16*)out)[(size_t)m * D + nn] = f2bf(v);
          } else if (seg == 1) {
            ((u16*)out2)[(size_t)m * D + nn] = f2bf(v);
          } else {
            const int bb = m >> 10, t = m & 1023, hh = nn >> 6, hd = nn & 63;
            ((u16*)out3)[((size_t)(bb * H + hh) * HD + hd) * T + t] = f2bf(v);
          }
        }
      }
    }
  }
}

// ---------------- flash attention (causal), Q/K plain [MM,D], V^T [B,H,HD,T] ----------------
__global__ __launch_bounds__(256) void attn_kernel(
    const u16* __restrict__ Q, const u16* __restrict__ Kc,
    const u16* __restrict__ Vt, u16* __restrict__ Oc)
{
  __shared__ u16 Pl[4][32 * 72];   // per-wave P tile, row stride 72 bf16 = 144B (9*16B)

  const int lane = threadIdx.x & 63, w = threadIdx.x >> 6;
  const int rlow = lane & 15, kgrp = lane >> 4;
  const int bh = blockIdx.x, bb = bh >> 4, hh = bh & 15;
  const int q0 = blockIdx.y * 128;
  const int wmin = q0 + w * 32;            // this wave's first q row

  // Q fragments hoisted to registers
  bf16x8 qf[2][2];
#pragma unroll
  for (int fm = 0; fm < 2; ++fm)
#pragma unroll
    for (int ks = 0; ks < 2; ++ks)
      qf[fm][ks] = *(const bf16x8*)(Q + (size_t)(bb * T + wmin + fm * 16 + rlow) * D
                                    + hh * HD + ks * 32 + kgrp * 8);

  f32x4 o[2][4] = {};
  float mrun[2][4], lrun[2][4];
#pragma unroll
  for (int fm = 0; fm < 2; ++fm)
#pragma unroll
    for (int i = 0; i < 4; ++i) { mrun[fm][i] = -1e30f; lrun[fm][i] = 0.f; }

  for (int kv0 = 0; kv0 <= wmin + 31; kv0 += 64) {
    // S = Q K^T
    f32x4 s[2][4] = {};
#pragma unroll
    for (int ks = 0; ks < 2; ++ks)
#pragma unroll
      for (int fn = 0; fn < 4; ++fn) {
        const bf16x8 kf = *(const bf16x8*)(Kc + (size_t)(bb * T + kv0 + fn * 16 + rlow) * D
                                           + hh * HD + ks * 32 + kgrp * 8);
#pragma unroll
        for (int fm = 0; fm < 2; ++fm)
          s[fm][fn] = __builtin_amdgcn_mfma_f32_16x16x32_bf16(qf[fm][ks], kf, s[fm][fn], 0, 0, 0);
      }

    const bool needmask = (kv0 + 63 > wmin);
#pragma unroll
    for (int fm = 0; fm < 2; ++fm) {
#pragma unroll
      for (int fn = 0; fn < 4; ++fn)
#pragma unroll
        for (int i = 0; i < 4; ++i) {
          float sv = s[fm][fn][i] * 0.125f;   // 1/sqrt(64)
          if (needmask) {
            const int qrow = wmin + fm * 16 + kgrp * 4 + i;
            const int kcol = kv0 + fn * 16 + rlow;
            if (kcol > qrow) sv = -1e30f;
          }
          s[fm][fn][i] = sv;
        }
      // online softmax: row spans the 16 lanes sharing kgrp
      float pm[4], rs[4];
#pragma unroll
      for (int i = 0; i < 4; ++i)
        pm[i] = fmaxf(fmaxf(s[fm][0][i], s[fm][1][i]), fmaxf(s[fm][2][i], s[fm][3][i]));
#pragma unroll
      for (int off = 1; off < 16; off <<= 1)
#pragma unroll
        for (int i = 0; i < 4; ++i) pm[i] = fmaxf(pm[i], __shfl_xor(pm[i], off));
      float mnew[4], corr[4];
#pragma unroll
      for (int i = 0; i < 4; ++i) {
        mnew[i] = fmaxf(mrun[fm][i], pm[i]);
        corr[i] = __expf(mrun[fm][i] - mnew[i]);
        mrun[fm][i] = mnew[i];
        rs[i] = 0.f;
      }
#pragma unroll
      for (int fn = 0; fn < 4; ++fn)
#pragma unroll
        for (int i = 0; i < 4; ++i) {
          const float pv = __expf(s[fm][fn][i] - mnew[i]);
          s[fm][fn][i] = pv;
          rs[i] += pv;
        }
#pragma unroll
      for (int off = 1; off < 16; off <<= 1)
#pragma unroll
        for (int i = 0; i < 4; ++i) rs[i] += __shfl_xor(rs[i], off);
#pragma unroll
      for (int i = 0; i < 4; ++i) lrun[fm][i] = lrun[fm][i] * corr[i] + rs[i];
#pragma unroll
      for (int fn = 0; fn < 4; ++fn)
#pragma unroll
        for (int i = 0; i < 4; ++i) o[fm][fn][i] *= corr[i];
      // P (C-layout) -> LDS for A-fragment re-read (same wave only; no barrier needed)
#pragma unroll
      for (int fn = 0; fn < 4; ++fn)
#pragma unroll
        for (int i = 0; i < 4; ++i)
          Pl[w][(fm * 16 + kgrp * 4 + i) * 72 + fn * 16 + rlow] = f2bf(s[fm][fn][i]);
    }

    // O += P V  (B-operand = V^T[n=hd][k=kv], contiguous 16B)
#pragma unroll
    for (int ks = 0; ks < 2; ++ks) {
      bf16x8 pa[2];
#pragma unroll
      for (int fm = 0; fm < 2; ++fm)
        pa[fm] = *(const bf16x8*)((const char*)Pl[w] + (fm * 16 + rlow) * 144 + ks * 64 + kgrp * 16);
#pragma unroll
      for (int fn = 0; fn < 4; ++fn) {
        const bf16x8 vb = *(const bf16x8*)(Vt + ((size_t)(bb * H + hh) * HD + fn * 16 + rlow) * T
                                           + kv0 + ks * 32 + kgrp * 8);
#pragma unroll
        for (int fm = 0; fm < 2; ++fm)
          o[fm][fn] = __builtin_amdgcn_mfma_f32_16x16x32_bf16(pa[fm], vb, o[fm][fn], 0, 0, 0);
      }
    }
  }

#pragma unroll
  for (int fm = 0; fm < 2; ++fm)
#pragma unroll
    for (int i = 0; i < 4; ++i) {
      const int qrow = wmin + fm * 16 + kgrp * 4 + i;
      const float inv = 1.0f / lrun[fm][i];
#pragma unroll
      for (int fn = 0; fn < 4; ++fn)
        Oc[(size_t)(bb * T + qrow) * D + hh * HD + fn * 16 + rlow] = f2bf(o[fm][fn][i] * inv);
    }
}

// ---------------- LayerNorm (row=1024), writes fp32 + bf16 ----------------
__global__ __launch_bounds__(256) void ln_kernel(
    const float* __restrict__ r, const float* __restrict__ sc, const float* __restrict__ bi,
    float* __restrict__ hout, u16* __restrict__ hb)
{
  const int row = blockIdx.x, tid = threadIdx.x;
  const float4 v = ((const float4*)(r + (size_t)row * D))[tid];
  float s  = v.x + v.y + v.z + v.w;
  float sq = v.x * v.x + v.y * v.y + v.z * v.z + v.w * v.w;
#pragma unroll
  for (int off = 1; off < 64; off <<= 1) { s += __shfl_xor(s, off); sq += __shfl_xor(sq, off); }
  __shared__ float red[2][4];
  const int w = tid >> 6, lane = tid & 63;
  if (lane == 0) { red[0][w] = s; red[1][w] = sq; }
  __syncthreads();
  const float S  = red[0][0] + red[0][1] + red[0][2] + red[0][3];
  const float SQ = red[1][0] + red[1][1] + red[1][2] + red[1][3];
  const float mean = S * (1.0f / D);
  const float var  = SQ * (1.0f / D) - mean * mean;
  const float inv  = rsqrtf(var + LNEPS);
  const float4 s4 = ((const float4*)sc)[tid];
  const float4 b4 = ((const float4*)bi)[tid];
  float4 y;
  y.x = (v.x - mean) * inv * s4.x + b4.x;
  y.y = (v.y - mean) * inv * s4.y + b4.y;
  y.z = (v.z - mean) * inv * s4.z + b4.z;
  y.w = (v.w - mean) * inv * s4.w + b4.w;
  ((float4*)(hout + (size_t)row * D))[tid] = y;
  ushort4 hv;
  hv.x = f2bf(y.x); hv.y = f2bf(y.y); hv.z = f2bf(y.z); hv.w = f2bf(y.w);
  ((ushort4*)(hb + (size_t)row * D))[tid] = hv;
}

// ---------------- embedding: h = word_emb[x] + pos_emb[t] ----------------
__global__ __launch_bounds__(256) void embed_kernel(
    const int* __restrict__ x, const float* __restrict__ we, const float* __restrict__ pe,
    float* __restrict__ h, u16* __restrict__ hb)
{
  const int row = blockIdx.x, tid = threadIdx.x;
  const int t = row & (T - 1);
  const int tok = x[row];
  const float4 a = ((const float4*)(we + (size_t)tok * D))[tid];
  const float4 p = ((const float4*)(pe + (size_t)t * D))[tid];
  float4 y = {a.x + p.x, a.y + p.y, a.z + p.z, a.w + p.w};
  ((float4*)(h + (size_t)row * D))[tid] = y;
  ushort4 hv;
  hv.x = f2bf(y.x); hv.y = f2bf(y.y); hv.z = f2bf(y.z); hv.w = f2bf(y.w);
  ((ushort4*)(hb + (size_t)row * D))[tid] = hv;
}

// ---------------- transpose + fp32->bf16 cast: in[R,C] -> out[C,R] ----------------
__global__ __launch_bounds__(256) void transpose_cast_kernel(
    const float* __restrict__ in, u16* __restrict__ outT, int R, int C)
{
  __shared__ float tile[32][33];
  const int tx = threadIdx.x, ty = threadIdx.y;
  const int x0 = blockIdx.x * 32, y0 = blockIdx.y * 32;
#pragma unroll
  for (int j = 0; j < 32; j += 8)
    tile[ty + j][tx] = in[(size_t)(y0 + ty + j) * C + x0 + tx];
  __syncthreads();
#pragma unroll
  for (int j = 0; j < 32; j += 8)
    outT[(size_t)(x0 + ty + j) * R + y0 + tx] = f2bf(tile[tx][ty + j]);
}

// batched D x D transpose: z=0,1,2 -> wq,wk,wv into dqkv rows [z*D, z*D+D); z=3 -> wo into dwo
__global__ __launch_bounds__(256) void transpose_cast4_kernel(
    const float* __restrict__ s0, const float* __restrict__ s1,
    const float* __restrict__ s2, const float* __restrict__ s3,
    u16* __restrict__ dqkv, u16* __restrict__ dwo)
{
  __shared__ float tile[32][33];
  const int z = blockIdx.z;
  const float* in = (z == 0) ? s0 : (z == 1) ? s1 : (z == 2) ? s2 : s3;
  u16* out = (z < 3) ? dqkv + (size_t)z * D * D : dwo;
  const int tx = threadIdx.x, ty = threadIdx.y;
  const int x0 = blockIdx.x * 32, y0 = blockIdx.y * 32;
#pragma unroll
  for (int j = 0; j < 32; j += 8)
    tile[ty + j][tx] = in[(size_t)(y0 + ty + j) * D + x0 + tx];
  __syncthreads();
#pragma unroll
  for (int j = 0; j < 32; j += 8)
    out[(size_t)(x0 + ty + j) * D + y0 + tx] = f2bf(tile[tx][ty + j]);
}

// ---------------- launcher ----------------
extern "C" void kernel_launch(void* const* d_in, const int* in_sizes, int n_in,
                              void* d_out, int out_size, void* d_ws, size_t ws_size,
                              hipStream_t stream)
{
  const int*   x    = (const int*)  d_in[0];
  const float* wemb = (const float*)d_in[1];
  const float* pemb = (const float*)d_in[2];
  const float* wq = (const float*)d_in[3];  const float* bq = (const float*)d_in[4];
  const float* wk = (const float*)d_in[5];  const float* bk = (const float*)d_in[6];
  const float* wv = (const float*)d_in[7];  const float* bv = (const float*)d_in[8];
  const float* wo = (const float*)d_in[9];  const float* bo = (const float*)d_in[10];
  const float* ln1s = (const float*)d_in[11]; const float* ln1b = (const float*)d_in[12];
  const float* w1 = (const float*)d_in[13]; const float* b1 = (const float*)d_in[14];
  const float* w2 = (const float*)d_in[15]; const float* b2 = (const float*)d_in[16];
  const float* ln2s = (const float*)d_in[17]; const float* ln2b = (const float*)d_in[18];

  // workspace layout (per-layer weight buffers reused; activations unioned)
  char* p = (char*)d_ws;
  auto take = [&](size_t bytes) { char* q = p; p += (bytes + 255) & ~(size_t)255; return q; };
  u16*  wqkvT = (u16*)take((size_t)3 * D * D * 2); // [3D, D]
  u16*  woT   = (u16*)take((size_t)D * D * 2);
  u16*  w1T   = (u16*)take((size_t)D * DFF * 2);   // [DFF, D]
  u16*  w2T   = (u16*)take((size_t)D * DFF * 2);   // [D, DFF]
  float* h    = (float*)take((size_t)MM * D * 4);
  float* rbuf = (float*)take((size_t)MM * D * 4);
  u16*  hb    = (u16*)take((size_t)MM * D * 2);
  char* uni   = (char*)take((size_t)MM * DFF * 2); // {qb,kb,vT,attn} OR {ff1}
  u16* qb  = (u16*)uni;
  u16* kb  = qb  + (size_t)MM * D;
  u16* vTb = kb  + (size_t)MM * D;
  u16* atb = vTb + (size_t)MM * D;
  u16* f1b = (u16*)uni;
  (void)ws_size; (void)in_sizes; (void)n_in; (void)out_size;

  const dim3 blk256(256);
  const dim3 tb(32, 8);

  embed_kernel<<<MM, blk256, 0, stream>>>(x, wemb, pemb, h, hb);

  for (int l = 0; l < L; ++l) {
    const size_t oDD = (size_t)l * D * D, oD = (size_t)l * D;
    const size_t oDF = (size_t)l * D * DFF, oF = (size_t)l * DFF;

    transpose_cast4_kernel<<<dim3(D / 32, D / 32, 4), tb, 0, stream>>>(
        wq + oDD, wk + oDD, wv + oDD, wo + oDD, wqkvT, woT);
    transpose_cast_kernel<<<dim3(DFF / 32, D / 32), tb, 0, stream>>>(w1 + oDF, w1T, D, DFF);
    transpose_cast_kernel<<<dim3(D / 32, DFF / 32), tb, 0, stream>>>(w2 + oDF, w2T, DFF, D);

    // fused QKV: N = 3072
    gemm_kernel<4><<<dim3(3 * D / 128, MM / 128), blk256, 0, stream>>>(
        hb, wqkvT, bq + oD, bk + oD, bv + oD, nullptr, qb, kb, vTb, MM, 3 * D, D);

    attn_kernel<<<dim3(B * H, T / 128), blk256, 0, stream>>>(qb, kb, vTb, atb);

    gemm_kernel<3><<<dim3(D / 128, MM / 128), blk256, 0, stream>>>(
        atb, woT, bo + oD, nullptr, nullptr, h, rbuf, nullptr, nullptr, MM, D, D);
    ln_kernel<<<MM, blk256, 0, stream>>>(rbuf, ln1s + oD, ln1b + oD, h, hb);

    gemm_kernel<2><<<dim3(DFF / 128, MM / 128), blk256, 0, stream>>>(
        hb, w1T, b1 + oF, nullptr, nullptr, nullptr, f1b, nullptr, nullptr, MM, DFF, D);
    gemm_kernel<3><<<dim3(D / 128, MM / 128), blk256, 0, stream>>>(
        f1b, w2T, b2 + oD, nullptr, nullptr, h, rbuf, nullptr, nullptr, MM, D, DFF);

    float* htgt = (l == L - 1) ? (float*)d_out : h;
    ln_kernel<<<MM, blk256, 0, stream>>>(rbuf, ln2s + oD, ln2b + oD, htgt, hb);
  }
}